// Round 5
// baseline (236.252 us; speedup 1.0000x reference)
//
#include <hip/hip_runtime.h>
#include <hip/hip_bf16.h>

#define N_ATOMS 32768

typedef __attribute__((ext_vector_type(4))) float f32x4;
typedef __attribute__((ext_vector_type(8))) short bf16x8;
typedef unsigned short u16;

__device__ __forceinline__ u16 f2b(float f) {
    union { __hip_bfloat16 b; u16 u; } c;
    c.b = __float2bfloat16(f);
    return c.u;
}
__device__ __forceinline__ float b2f(u16 u) {
    union { unsigned int i; float f; } c;
    c.i = ((unsigned int)u) << 16;
    return c.f;
}

#define GLDS16(src, dst) __builtin_amdgcn_global_load_lds( \
    (const __attribute__((address_space(1))) void*)(src),  \
    (__attribute__((address_space(3))) void*)(dst), 16, 0, 0)

// ---------------- conversion kernels ----------------

__global__ void convx_kernel(const float* __restrict__ x,
                             u16* __restrict__ xhi, u16* __restrict__ xlo) {
    size_t i = (size_t)(blockIdx.x * 256 + threadIdx.x) * 8;
    float4 v0 = *(const float4*)(x + i);
    float4 v1 = *(const float4*)(x + i + 4);
    float v[8] = {v0.x, v0.y, v0.z, v0.w, v1.x, v1.y, v1.z, v1.w};
    bf16x8 rh, rl;
#pragma unroll
    for (int j = 0; j < 8; ++j) {
        u16 h = f2b(v[j]);
        rh[j] = (short)h;
        rl[j] = (short)f2b(v[j] - b2f(h));
    }
    *(bf16x8*)(xhi + i) = rh;
    *(bf16x8*)(xlo + i) = rl;
}

__global__ void convw_kernel(const float* __restrict__ w1l, const float* __restrict__ w2l,
                             const float* __restrict__ w3l, const float* __restrict__ w1r,
                             const float* __restrict__ w2r,
                             u16* __restrict__ W1LThi, u16* __restrict__ W1LTlo,
                             u16* __restrict__ W1RT,
                             u16* __restrict__ W2LThi, u16* __restrict__ W2LTlo,
                             u16* __restrict__ W2RT,
                             u16* __restrict__ W3LThi, u16* __restrict__ W3LTlo) {
    int i = blockIdx.x * 256 + threadIdx.x;
    if (i < 131072) {                       // w1_lat [256,512] -> [512][256] hi/lo
        int n = i >> 8, k = i & 255;
        float v = w1l[k * 512 + n];
        u16 h = f2b(v);
        W1LThi[i] = h;
        W1LTlo[i] = f2b(v - b2f(h));
    } else if (i < 262144) {                // w1_ro -> [512][256] bf16
        int j = i - 131072;
        int n = j >> 8, k = j & 255;
        W1RT[j] = f2b(w1r[k * 512 + n]);
    } else if (i < 524288) {                // w2_lat [512,512] -> hi/lo
        int j = i - 262144;
        int n = j >> 9, k = j & 511;
        float v = w2l[k * 512 + n];
        u16 h = f2b(v);
        W2LThi[j] = h;
        W2LTlo[j] = f2b(v - b2f(h));
    } else if (i < 786432) {                // w2_ro -> bf16
        int j = i - 524288;
        int n = j >> 9, k = j & 511;
        W2RT[j] = f2b(w2r[k * 512 + n]);
    } else if (i < 851968) {                // w3_lat [512,128] -> [128][512] hi/lo
        int j = i - 786432;
        int n = j >> 9, k = j & 511;
        float v = w3l[k * 128 + n];
        u16 h = f2b(v);
        W3LThi[j] = h;
        W3LTlo[j] = f2b(v - b2f(h));
    }
}

// ---------------- 4-phase counted-vmcnt MFMA GEMM ----------------
// C = act( scale * sum_seg Aseg @ Bseg^T ).  BM=256, BN=NF*64, BK=64,
// 512 threads = 8 waves (2M x 4N), per-wave 128 x NF*16 output (acc[8][NF]).
// LDS double-buffered; staging split into 64-row gload_lds instructions
// issued in order [B0,B1,(B2,B3),A0,A2,A1,A3]; one pair staged per phase.
// Per-wave reads are confined (A-half wm, B-quarter wn), so vmcnt(4) at
// P0/P1 covers all reads while 4 loads stay in flight across the barrier
// (T3+T4); no vmcnt(0) drain in the main loop. setprio around MFMA (T5).
// NSEG=3: K-segments (Ahi,Bhi),(Alo,Bhi),(Ahi,Blo) = split-bf16 ~f32.
// OUTK: 0 = f32, 1 = bf16, 2 = split hi/lo bf16.
template<int NSEG, int GX, int NF, bool SILU, int OUTK>
__global__ void __launch_bounds__(512, 2) gemm_p4(
        const u16* __restrict__ Ahi, const u16* __restrict__ Alo,
        const u16* __restrict__ Bhi, const u16* __restrict__ Blo,
        void* __restrict__ Chi, void* __restrict__ Clo,
        int ldc, int K, float scale) {
    __shared__ __align__(16) u16 lA[2][256 * 64];
    __shared__ __align__(16) u16 lB[2][NF * 64 * 64];
    const int tid = threadIdx.x;
    const int lane = tid & 63;
    const int wid = tid >> 6;
    const int wm = wid >> 2;            // 0..1 -> 128-row half
    const int wn = wid & 3;             // 0..3 -> NF*16-col quarter
    const int rlane = lane & 15;
    const int kc = lane >> 4;           // 0..3
    const int cps = rlane & 7;
    const int srow = tid >> 3;          // 0..63
    const int scp = tid & 7;

    // bijective XCD swizzle (grid % 8 == 0)
    const int nwg = gridDim.x;
    const int bid = blockIdx.x;
    const int wg = (bid & 7) * (nwg >> 3) + (bid >> 3);
    const int bn = (wg % GX) * (NF * 64);
    const int bm = (wg / GX) * 256;

    const int kt = K >> 6;
    const int NT = NSEG * kt;

    // stage one 64-row instruction of A (c in 0..3) / B (c in 0..NF-1)
#define STA(tt, bb, c) do {                                                   \
        int seg_ = (NSEG == 1) ? 0 : (((tt) >= kt) + ((tt) >= 2 * kt));       \
        const u16* As_ = (NSEG == 1) ? Ahi : (seg_ == 1 ? Alo : Ahi);         \
        int k0_ = ((tt) - seg_ * kt) << 6;                                    \
        int row_ = (c) * 64 + srow;                                           \
        GLDS16(As_ + (size_t)(bm + row_) * K + k0_ + (scp ^ (srow & 7)) * 8,  \
               &lA[bb][row_ * 64 + scp * 8]);                                 \
    } while (0)
#define STB(tt, bb, c) do {                                                   \
        int seg_ = (NSEG == 1) ? 0 : (((tt) >= kt) + ((tt) >= 2 * kt));       \
        const u16* Bs_ = (NSEG == 1) ? Bhi : (seg_ == 2 ? Blo : Bhi);         \
        int k0_ = ((tt) - seg_ * kt) << 6;                                    \
        int row_ = (c) * 64 + srow;                                           \
        GLDS16(Bs_ + (size_t)(bn + row_) * K + k0_ + (scp ^ (srow & 7)) * 8,  \
               &lB[bb][row_ * 64 + scp * 8]);                                 \
    } while (0)
#define READ_AF(dst, bb, mh, ks) do {                                         \
        _Pragma("unroll")                                                     \
        for (int m_ = 0; m_ < 4; ++m_) {                                      \
            int row_ = wm * 128 + (mh) * 64 + m_ * 16 + rlane;                \
            dst[m_] = *(const bf16x8*)&lA[bb][row_ * 64 + (((ks) * 4 + kc) ^ cps) * 8]; \
        }                                                                     \
    } while (0)
#define READ_BF(dst, bb, ks) do {                                             \
        _Pragma("unroll")                                                     \
        for (int n_ = 0; n_ < NF; ++n_) {                                     \
            int row_ = wn * (NF * 16) + n_ * 16 + rlane;                      \
            dst[n_] = *(const bf16x8*)&lB[bb][row_ * 64 + (((ks) * 4 + kc) ^ cps) * 8]; \
        }                                                                     \
    } while (0)
#define MFMA4(af_, bf_, mh) do {                                              \
        __builtin_amdgcn_s_setprio(1);                                        \
        _Pragma("unroll")                                                     \
        for (int m_ = 0; m_ < 4; ++m_)                                        \
            _Pragma("unroll")                                                 \
            for (int n_ = 0; n_ < NF; ++n_)                                   \
                acc[(mh) * 4 + m_][n_] = __builtin_amdgcn_mfma_f32_16x16x32_bf16( \
                    af_[m_], bf_[n_], acc[(mh) * 4 + m_][n_], 0, 0, 0);       \
        __builtin_amdgcn_s_setprio(0);                                        \
    } while (0)
#define LGKM0 do {                                                            \
        asm volatile("s_waitcnt lgkmcnt(0)" ::: "memory");                    \
        __builtin_amdgcn_sched_barrier(0);                                    \
    } while (0)

// one K-tile: 4 phases; PF = prefetch tile tt+1 into buffer cur^1
#define TILE(tt, cur, PF) do {                                                \
        __builtin_amdgcn_s_barrier();                                         \
        bf16x8 bfA[NF], bfB[NF], af0[4], af1[4], af2[4], af3[4];              \
        /* P0: (ks0, mh0) */                                                  \
        if (PF) { STB(tt + 1, (cur) ^ 1, 0); STB(tt + 1, (cur) ^ 1, 1);       \
                  asm volatile("s_waitcnt vmcnt(4)" ::: "memory"); }          \
        else    { asm volatile("s_waitcnt vmcnt(0)" ::: "memory"); }          \
        READ_BF(bfA, cur, 0); READ_AF(af0, cur, 0, 0);                        \
        LGKM0; MFMA4(af0, bfA, 0);                                            \
        /* P1: (ks0, mh1) */                                                  \
        if (PF) { if (NF == 4) { STB(tt + 1, (cur) ^ 1, 2); STB(tt + 1, (cur) ^ 1, 3); } \
                  else         { STA(tt + 1, (cur) ^ 1, 0); STA(tt + 1, (cur) ^ 1, 2); } \
                  asm volatile("s_waitcnt vmcnt(4)" ::: "memory"); }          \
        READ_AF(af1, cur, 1, 0);                                              \
        LGKM0; MFMA4(af1, bfA, 1);                                            \
        /* P2: (ks1, mh0) */                                                  \
        if (PF) { if (NF == 4) { STA(tt + 1, (cur) ^ 1, 0); STA(tt + 1, (cur) ^ 1, 2); } \
                  else         { STA(tt + 1, (cur) ^ 1, 1); STA(tt + 1, (cur) ^ 1, 3); } } \
        READ_BF(bfB, cur, 1); READ_AF(af2, cur, 0, 1);                        \
        LGKM0; MFMA4(af2, bfB, 0);                                            \
        /* P3: (ks1, mh1) */                                                  \
        if (PF) { if (NF == 4) { STA(tt + 1, (cur) ^ 1, 1); STA(tt + 1, (cur) ^ 1, 3); } } \
        READ_AF(af3, cur, 1, 1);                                              \
        LGKM0; MFMA4(af3, bfB, 1);                                            \
    } while (0)

    f32x4 acc[8][NF] = {};

    // prologue: stage tile 0 in the SAME per-wave order the waits assume
    STB(0, 0, 0); STB(0, 0, 1);
    if (NF == 4) { STB(0, 0, 2); STB(0, 0, 3); }
    STA(0, 0, 0); STA(0, 0, 2); STA(0, 0, 1); STA(0, 0, 3);

    for (int t = 0; t < NT - 1; ++t)
        TILE(t, t & 1, true);
    TILE(NT - 1, (NT - 1) & 1, false);

#undef TILE
#undef LGKM0
#undef MFMA4
#undef READ_BF
#undef READ_AF
#undef STB
#undef STA

    // epilogue: C/D layout col = lane&15, row = (lane>>4)*4 + reg
#pragma unroll
    for (int m = 0; m < 8; ++m) {
        int grow0 = bm + wm * 128 + m * 16 + ((lane >> 4) << 2);
#pragma unroll
        for (int n = 0; n < NF; ++n) {
            int gcol = bn + wn * (NF * 16) + n * 16 + rlane;
#pragma unroll
            for (int r = 0; r < 4; ++r) {
                float v = acc[m][n][r] * scale;
                if constexpr (SILU) v = v / (1.0f + __expf(-v));
                size_t idx = (size_t)(grow0 + r) * ldc + gcol;
                if constexpr (OUTK == 0) {
                    ((float*)Chi)[idx] = v;
                } else if constexpr (OUTK == 1) {
                    ((u16*)Chi)[idx] = f2b(v);
                } else {
                    u16 h = f2b(v);
                    ((u16*)Chi)[idx] = h;
                    ((u16*)Clo)[idx] = f2b(v - b2f(h));
                }
            }
        }
    }
}

// ---------------- inv_out: H2R [32768,512] bf16 @ w3_ro [512,2] f32 ----------------
__global__ void invout_kernel(const u16* __restrict__ H2b,
                              const float* __restrict__ w3,
                              float* __restrict__ out) {
    int g = blockIdx.x * 256 + threadIdx.x;
    int n = g >> 6;
    int lane = g & 63;
    bf16x8 hv = *(const bf16x8*)(H2b + (size_t)n * 512 + lane * 8);
    float s0 = 0.f, s1 = 0.f;
#pragma unroll
    for (int j = 0; j < 8; ++j) {
        float hf = b2f((u16)hv[j]);
        int k = lane * 8 + j;
        s0 = fmaf(hf, w3[2 * k], s0);
        s1 = fmaf(hf, w3[2 * k + 1], s1);
    }
#pragma unroll
    for (int off = 32; off > 0; off >>= 1) {
        s0 += __shfl_xor(s0, off);
        s1 += __shfl_xor(s1, off);
    }
    if (lane == 0) {
        const float s = 0.04419417382415922f;   // 1/sqrt(512)
        out[2 * n] = s0 * s;
        out[2 * n + 1] = s1 * s;
    }
}

// ---------------- per-atom equivariant output ----------------
__global__ void eq_kernel(const float* __restrict__ eqf, const float* __restrict__ wgt,
                          const int* __restrict__ types, const float* __restrict__ bond,
                          float* __restrict__ out) {
    int t = blockIdx.x * 256 + threadIdx.x;   // 131072 = 32768*4
    int n = t >> 2, v = t & 3;
    const float* e = eqf + (size_t)n * 96;
    const float* w = wgt + (size_t)n * 128 + v;
    float a0 = 0.f, a1 = 0.f, a2 = 0.f;
#pragma unroll
    for (int u = 0; u < 32; ++u) {
        float wv = w[u * 4];
        a0 = fmaf(e[u * 3 + 0], wv, a0);
        a1 = fmaf(e[u * 3 + 1], wv, a1);
        a2 = fmaf(e[u * 3 + 2], wv, a2);
    }
    const float s = 0.17677669529663687f;   // 1/sqrt(32)
    a0 *= s; a1 *= s; a2 *= s;
    float norm = sqrtf(a0 * a0 + a1 * a1 + a2 * a2) + 1e-10f;
    float bl = bond[types[n] * 4 + v];
    float r0 = a0 / norm, r1 = a1 / norm, r2 = a2 / norm;
    if (isnan(r0)) r0 = 0.f;
    if (isnan(r1)) r1 = 0.f;
    if (isnan(r2)) r2 = 0.f;
    out[(size_t)n * 12 + v * 3 + 0] = r0 * bl;
    out[(size_t)n * 12 + v * 3 + 1] = r1 * bl;
    out[(size_t)n * 12 + v * 3 + 2] = r2 * bl;
}

// ---------------- launcher ----------------
extern "C" void kernel_launch(void* const* d_in, const int* in_sizes, int n_in,
                              void* d_out, int out_size, void* d_ws, size_t ws_size,
                              hipStream_t stream) {
    const float* inv  = (const float*)d_in[0];
    const float* eqf  = (const float*)d_in[1];
    const int*   typs = (const int*)d_in[2];
    const float* w1l  = (const float*)d_in[3];
    const float* w2l  = (const float*)d_in[4];
    const float* w3l  = (const float*)d_in[5];
    const float* w1r  = (const float*)d_in[6];
    const float* w2r  = (const float*)d_in[7];
    const float* w3r  = (const float*)d_in[8];
    const float* bond = (const float*)d_in[9];

    char* ws = (char*)d_ws;
    const size_t MB = 1024 * 1024, KB = 1024;
    // live-range-aliased memory map:
    u16* XHI   = (u16*)(ws);            // 16MB [32768][256]
    u16* XLO   = (u16*)(ws + 16 * MB);  // 16MB
    u16* H1R   = (u16*)(ws + 32 * MB);  // 32MB [32768][512]
    u16* H1Lhi = (u16*)(ws + 64 * MB);  // 32MB
    u16* H1Llo = (u16*)(ws + 96 * MB);  // 32MB
    u16* H2R   = (u16*)(ws + 128 * MB); // 32MB
    u16* H2Lhi = (u16*)(ws);            // 32MB, aliases XHI+XLO (dead after ro L1)
    u16* H2Llo = (u16*)(ws + 32 * MB);  // 32MB, aliases H1R (dead after ro L2)
    float* WGT = (float*)(ws + 64 * MB);// 16MB, aliases H1Lhi (dead after lat L2)
    char* wb = ws + 160 * MB;
    u16* W1LThi = (u16*)(wb);               // 256KB [512][256]
    u16* W1LTlo = (u16*)(wb + 256 * KB);    // 256KB
    u16* W1RT   = (u16*)(wb + 512 * KB);    // 256KB
    u16* W2LThi = (u16*)(wb + 768 * KB);    // 512KB [512][512]
    u16* W2LTlo = (u16*)(wb + 1280 * KB);   // 512KB
    u16* W2RT   = (u16*)(wb + 1792 * KB);   // 512KB
    u16* W3LThi = (u16*)(wb + 2304 * KB);   // 128KB [128][512]
    u16* W3LTlo = (u16*)(wb + 2432 * KB);   // 128KB

    float* out_inv = (float*)d_out;                 // [32768][2]
    float* out_eq  = (float*)d_out + N_ATOMS * 2;   // [32768][4][3]

    const float s256 = 0.0625f;                 // 1/sqrt(256)
    const float s512 = 0.04419417382415922f;    // 1/sqrt(512)

    convx_kernel<<<dim3(4096), dim3(256), 0, stream>>>(inv, XHI, XLO);
    convw_kernel<<<dim3(3328), dim3(256), 0, stream>>>(w1l, w2l, w3l, w1r, w2r,
        W1LThi, W1LTlo, W1RT, W2LThi, W2LTlo, W2RT, W3LThi, W3LTlo);

    // lat L1 (split): [32768,256] -> H1L hi/lo (silu)   grid 128x2 = 256
    gemm_p4<3, 2, 4, true, 2><<<dim3(256), dim3(512), 0, stream>>>(
        XHI, XLO, W1LThi, W1LTlo, H1Lhi, H1Llo, 512, 256, s256);
    // ro L1 (bf16): -> H1R (silu)
    gemm_p4<1, 2, 4, true, 1><<<dim3(256), dim3(512), 0, stream>>>(
        XHI, nullptr, W1RT, nullptr, H1R, nullptr, 512, 256, s256);
    // ro L2 (bf16): -> H2R (silu)   [must precede lat L2: H2Llo aliases H1R]
    gemm_p4<1, 2, 4, true, 1><<<dim3(256), dim3(512), 0, stream>>>(
        H1R, nullptr, W2RT, nullptr, H2R, nullptr, 512, 512, s512);
    // lat L2 (split): -> H2L hi/lo (silu)
    gemm_p4<3, 2, 4, true, 2><<<dim3(256), dim3(512), 0, stream>>>(
        H1Lhi, H1Llo, W2LThi, W2LTlo, H2Lhi, H2Llo, 512, 512, s512);
    // lat L3 (split): [32768,512] @ [512,128] -> WGT f32 (no act)  BN=128, grid 128
    gemm_p4<3, 1, 2, false, 0><<<dim3(128), dim3(512), 0, stream>>>(
        H2Lhi, H2Llo, W3LThi, W3LTlo, WGT, nullptr, 128, 512, s512);
    // ro L3
    invout_kernel<<<dim3(8192), dim3(256), 0, stream>>>(H2R, w3r, out_inv);
    // equivariant epilogue
    eq_kernel<<<dim3(512), dim3(256), 0, stream>>>(eqf, WGT, typs, bond, out_eq);
}